// Round 8
// baseline (163.170 us; speedup 1.0000x reference)
//
#include <hip/hip_runtime.h>

#define B_ 8
#define C_ 128
#define W_ 4096
#define D_ 16
// D^-0.5 * log2(e): folded into Wq/bq; exp2 domain (v_exp_f32)
#define SCALE2 0.3606737602222409f

typedef short bf16x8 __attribute__((ext_vector_type(8)));
typedef float f32x4 __attribute__((ext_vector_type(4)));
typedef float f32x16 __attribute__((ext_vector_type(16)));

__device__ __forceinline__ unsigned short f2bf(float f) {
    unsigned int u = __float_as_uint(f);
    u += 0x7fffu + ((u >> 16) & 1u);
    return (unsigned short)(u >> 16);
}
__device__ __forceinline__ float bf2f(unsigned short h) {
    return __uint_as_float(((unsigned int)h) << 16);
}
// pack two f32 -> u32 of 2 bf16 (TRUNCATED) in ONE v_perm_b32
__device__ __forceinline__ unsigned int pk2bf(float lo, float hi) {
    return __builtin_amdgcn_perm(__float_as_uint(hi), __float_as_uint(lo), 0x07060302u);
}
__device__ __forceinline__ bf16x8 uint4_as_bf8(uint4 u) {
    union { uint4 u; bf16x8 v; } t;
    t.u = u;
    return t.v;
}
// load 8 consecutive f32, scale, truncate-pack to one bf16x8 fragment
__device__ __forceinline__ bf16x8 ld8w(const float* p, float sc) {
    float4 lo = *(const float4*)p, hi = *(const float4*)(p + 4);
    union { uint4 u; bf16x8 v; } t;
    t.u = make_uint4(pk2bf(lo.x * sc, lo.y * sc), pk2bf(lo.z * sc, lo.w * sc),
                     pk2bf(hi.x * sc, hi.y * sc), pk2bf(hi.z * sc, hi.w * sc));
    return t.v;
}
// exp2 8 S-values (C-regs r0..r0+7) -> one K=16 fragment as uint4
__device__ __forceinline__ uint4 exp2pkq(f32x16 s, int r0) {
    return make_uint4(
        pk2bf(__builtin_amdgcn_exp2f(s[r0+0]), __builtin_amdgcn_exp2f(s[r0+1])),
        pk2bf(__builtin_amdgcn_exp2f(s[r0+2]), __builtin_amdgcn_exp2f(s[r0+3])),
        pk2bf(__builtin_amdgcn_exp2f(s[r0+4]), __builtin_amdgcn_exp2f(s[r0+5])),
        pk2bf(__builtin_amdgcn_exp2f(s[r0+6]), __builtin_amdgcn_exp2f(s[r0+7])));
}
// LDS chunk swizzle for proj staging
__device__ __forceinline__ int xswz(int j, int c8) {
    return c8 ^ (j & 7) ^ ((j >> 3) & 7);
}

// ---------------- proj: q,k,v in one pass; weights converted inline ----------------
// qws2/kws2: [b][pos/32][h 0-1][pos%32][8 dims]  (dims h*8+i; K=16, no padding)
// vws2:      [b][jt][kf 0-1][h 0-1][c 128][8]    slot i -> j = jt*32 + kf*16+4h+(i&3)+8*(i>>2)
__global__ __launch_bounds__(256) void proj(
    const float* __restrict__ x,
    const float* __restrict__ Wq, const float* __restrict__ Wk, const float* __restrict__ Wv,
    const float* __restrict__ bqp, const float* __restrict__ bkp, const float* __restrict__ bvp,
    unsigned short* __restrict__ qws2, unsigned short* __restrict__ kws2,
    unsigned short* __restrict__ vws2)
{
    __shared__ unsigned short xbf[32 * 128];     // [j][c] swizzled chunks, 8KB
    __shared__ unsigned short outs[128 * 36];    // v bounce [c][j], 9KB
    __shared__ unsigned short qk_s[2][32][24];   // q/k bounce [qk][pos][dim], 3KB (row 48B)

    int b  = blockIdx.x & 7;
    int j0 = (blockIdx.x >> 3) * 32;
    int jt = j0 >> 5;
    int tid = threadIdx.x;
    int wid = tid >> 6, lane = tid & 63, n = lane & 15, q4 = lane >> 4;

    // stage x tile [128c][32j] -> bf16 LDS [j][c] swizzled; c-paired v_perm packs
    {
        unsigned int* xbf32 = (unsigned int*)xbf;
#pragma unroll
        for (int i = 0; i < 8; i++) {
            int p = tid + 256 * i;            // 2048 c-pair slots
            int c2 = p >> 5;                  // c = 2*c2, 2*c2+1
            int j  = p & 31;
            const float* xp = x + (size_t)(b * C_ + 2 * c2) * W_ + j0 + j;
            float lo = xp[0];
            float hi = xp[W_];
            xbf32[j * 64 + xswz(j, c2 >> 2) * 4 + (c2 & 3)] = pk2bf(lo, hi);
        }
    }
    __syncthreads();

    const f32x4 zero = {0.f, 0.f, 0.f, 0.f};
    f32x4 accv[2][2]; f32x4 accqk = zero;
#pragma unroll
    for (int os = 0; os < 2; os++)
#pragma unroll
        for (int js = 0; js < 2; js++) accv[os][js] = zero;

    int isK = wid >> 1;          // waves 0,1: q; waves 2,3: k
    int jsm = wid & 1;           // which j-tile this wave's q/k MFMA covers
    const float* wqk = isK ? Wk : Wq;
    const float qksc = isK ? 1.0f : SCALE2;

#pragma unroll
    for (int kk = 0; kk < 128; kk += 32) {
        bf16x8 av[2], aqkf, bx[2];
#pragma unroll
        for (int os = 0; os < 2; os++)
            av[os] = ld8w(Wv + (size_t)(wid * 32 + os * 16 + n) * 128 + kk + q4 * 8, 1.0f);
        aqkf = ld8w(wqk + (size_t)n * 128 + kk + q4 * 8, qksc);
#pragma unroll
        for (int js = 0; js < 2; js++) {
            int j = js * 16 + n;
            bx[js] = *(const bf16x8*)&xbf[j * 128 + xswz(j, (kk >> 3) + q4) * 8];
        }
#pragma unroll
        for (int os = 0; os < 2; os++)
#pragma unroll
            for (int js = 0; js < 2; js++)
                accv[os][js] = __builtin_amdgcn_mfma_f32_16x16x32_bf16(av[os], bx[js], accv[os][js], 0, 0, 0);
        accqk = __builtin_amdgcn_mfma_f32_16x16x32_bf16(aqkf, bx[jsm], accqk, 0, 0, 0);
    }

    // q/k epilogue -> qk_s (C layout: row d = q4*4+r, col pos = jsm*16+n)
    {
        int pos = jsm * 16 + n;
        const float* bias = isK ? bkp : bqp;
        float bsc = isK ? 1.0f : SCALE2;
#pragma unroll
        for (int r = 0; r < 4; r++)
            qk_s[isK][pos][q4 * 4 + r] = f2bf(accqk[r] + bias[q4 * 4 + r] * bsc);
    }

    // v epilogue -> outs [c][j]
    float bvv[2][4];
#pragma unroll
    for (int os = 0; os < 2; os++)
#pragma unroll
        for (int r = 0; r < 4; r++) bvv[os][r] = bvp[wid * 32 + os * 16 + q4 * 4 + r];
#pragma unroll
    for (int os = 0; os < 2; os++)
#pragma unroll
        for (int js = 0; js < 2; js++)
#pragma unroll
            for (int r = 0; r < 4; r++) {
                int c = wid * 32 + os * 16 + q4 * 4 + r;
                int j = js * 16 + n;
                outs[c * 36 + j] = f2bf(accv[os][js][r] + bvv[os][r]);
            }
    __syncthreads();

    // qws2/kws2 writers (128 tasks x 16B)
    if (tid < 128) {
        int qk = tid >> 6, hh = (tid >> 5) & 1, jl = tid & 31;
        uint4 v = *(const uint4*)&qk_s[qk][jl][hh * 8];
        unsigned short* dst = (qk ? kws2 : qws2)
            + (size_t)(b * 128 + jt) * 512 + hh * 256 + jl * 8;
        *(uint4*)dst = v;
    }
    // vws2 writers (512 tasks x 16B): slot i -> j = kf*16+4h+{0..3,8..11}
#pragma unroll
    for (int rep = 0; rep < 2; rep++) {
        int t = tid + rep * 256;
        int c = t & 127, sel = t >> 7;          // sel = kf*2+h
        int jb = (sel >> 1) * 16 + (sel & 1) * 4;
        uint2 lo = *(const uint2*)&outs[c * 36 + jb];
        uint2 hi = *(const uint2*)&outs[c * 36 + jb + 8];
        *(uint4*)(vws2 + ((size_t)(b * 128 + jt) * 4 + sel) * 1024 + c * 8) =
            make_uint4(lo.x, lo.y, hi.x, hi.y);
    }
}

// ---------------- row_stats: partial l-sums via 32x32x16, w split 4 ways ----------------
// rlp[wsp][b][W] = sum over w-quarter of exp2(s2[j,w])
__global__ __launch_bounds__(256) void row_stats(
    const unsigned short* __restrict__ qws2, const unsigned short* __restrict__ kws2,
    float* __restrict__ rlp)
{
    int blk = blockIdx.x;                // grid 1024
    int b = blk & 7;
    int j0 = ((blk >> 3) & 31) * 128;
    int wsp = blk >> 8;                  // 0..3
    int tid = threadIdx.x;
    int wid = tid >> 6, lane = tid & 63, wl = lane & 31, h = lane >> 5;

    const unsigned short* qb = qws2 + (size_t)b * 65536;
    const unsigned short* kb = kws2 + (size_t)b * 65536;
    int jt = (j0 >> 5) + wid;

    bf16x8 aq = *(const bf16x8*)(qb + (size_t)jt * 512 + h * 256 + wl * 8);
    f32x16 zero16 = {0.f,0.f,0.f,0.f,0.f,0.f,0.f,0.f,0.f,0.f,0.f,0.f,0.f,0.f,0.f,0.f};

    float lt[16];
#pragma unroll
    for (int r = 0; r < 16; r++) lt[r] = 0.f;

    bf16x8 bkc = *(const bf16x8*)(kb + (size_t)(wsp * 32) * 512 + h * 256 + wl * 8);
    for (int t = 0; t < 32; t++) {
        f32x16 s = __builtin_amdgcn_mfma_f32_32x32x16_bf16(aq, bkc, zero16, 0, 0, 0);
        int tn = wsp * 32 + ((t + 1) & 31);   // branchless wrap prefetch
        bkc = *(const bf16x8*)(kb + (size_t)tn * 512 + h * 256 + wl * 8);
#pragma unroll
        for (int r = 0; r < 16; r++) lt[r] += __builtin_amdgcn_exp2f(s[r]);
    }
    // reduce over 32 w-lanes (same half)
#pragma unroll
    for (int mask = 1; mask < 32; mask <<= 1)
#pragma unroll
        for (int r = 0; r < 16; r++) lt[r] += __shfl_xor(lt[r], mask, 64);
    if (wl == 0) {
        // C rows: r=4g+e -> j-local = e + 8g + 4h
#pragma unroll
        for (int g = 0; g < 4; g++) {
            f32x4 v = {lt[4*g+0], lt[4*g+1], lt[4*g+2], lt[4*g+3]};
            *(f32x4*)(rlp + (size_t)wsp * 32768 + (size_t)b * W_ + j0 + wid * 32 + 4 * h + 8 * g) = v;
        }
    }
}

// ---------------- vscale: v' = v * (1/l), finl inlined (rls never hits global) ----------------
__global__ __launch_bounds__(256) void vscale(unsigned short* __restrict__ vws2,
                                              const float* __restrict__ rlp)
{
    __shared__ float rl[16];
    int bi = blockIdx.x;                 // 0..2047
    int g0 = bi * 256;
    int kf = (g0 >> 8) & 1, jt = (g0 >> 9) & 127, b = g0 >> 16;
    int tid = threadIdx.x;
    if (tid < 16) {
        int idx = b * W_ + jt * 32 + kf * 16 + tid;
        float l = rlp[idx] + rlp[32768 + idx] + rlp[65536 + idx] + rlp[98304 + idx];
        rl[tid] = 1.0f / l;
    }
    __syncthreads();

    int g = g0 + tid;
    int hh = (g >> 7) & 1;
    float4 r0 = *(const float4*)&rl[4 * hh];        // slots 0-3: j = kf*16+4hh+{0..3}
    float4 r1 = *(const float4*)&rl[4 * hh + 8];    // slots 4-7: j = kf*16+4hh+8+{0..3}
    uint4 v = *(const uint4*)(vws2 + (size_t)g * 8);
    unsigned int o0 = pk2bf(bf2f((unsigned short)(v.x & 0xffffu)) * r0.x,
                            bf2f((unsigned short)(v.x >> 16))     * r0.y);
    unsigned int o1 = pk2bf(bf2f((unsigned short)(v.y & 0xffffu)) * r0.z,
                            bf2f((unsigned short)(v.y >> 16))     * r0.w);
    unsigned int o2 = pk2bf(bf2f((unsigned short)(v.z & 0xffffu)) * r1.x,
                            bf2f((unsigned short)(v.z >> 16))     * r1.y);
    unsigned int o3 = pk2bf(bf2f((unsigned short)(v.w & 0xffffu)) * r1.z,
                            bf2f((unsigned short)(v.w >> 16))     * r1.w);
    *(uint4*)(vws2 + (size_t)g * 8) = make_uint4(o0, o1, o2, o3);
}

// ---------------- attn_out: 8-wave pipeline, ONE barrier per 2 j-steps ----------------
// Block: 512 thr, tile 128c x 64w, j-step 128, 32 j-steps = 16 super-iters.
// 4 P-buffers (mod-4 rotation): super-iter T reads buffers {2T,2T+1}&3 while S
// writes {2T+2,2T+3}&3 — disjoint, so ONE __syncthreads per super-iter (17 vs 33).
// Epilogue red[] is ALIASED over the P-buffers (only live after the final barrier).
// vf prefetch 3-deep (X=cur, Y=next, Z=next2) keeps >=1-iter load distance.
// Occupancy is register-capped at 16 waves/CU (acc 32 + vf 48 + ~50 arch) — more
// blocks/CU is NOT reachable; this attacks the per-iter barrier stall instead.
__global__ __launch_bounds__(512, 4) void attn_out(
    const float* __restrict__ x, const unsigned short* __restrict__ qws2,
    const unsigned short* __restrict__ kws2, const unsigned short* __restrict__ vws2,
    float* __restrict__ out)
{
    __shared__ __align__(16) unsigned char smem[65536];
    uint4* p_u4 = (uint4*)smem;          // p[4][1024] uint4 = 64 KB (main loop)
    float* red  = (float*)smem;          // [128*68] f32 (epilogue only, aliased)

    int b  = blockIdx.x & 7;
    int w0 = (blockIdx.x >> 3) * 64;
    int tid = threadIdx.x;
    int wid = tid >> 6, lane = tid & 63, wl = lane & 31, h = lane >> 5;
    int cq = wid >> 1, kh = wid & 1;

    const unsigned short* qb  = qws2 + (size_t)b * 65536;
    const unsigned short* kb  = kws2 + (size_t)b * 65536;
    const uint4* vtb4 = (const uint4*)(vws2 + (size_t)b * 524288) + h * 128 + (cq * 32 + wl);
    const int qoff = h * 256 + wl * 8;   // short units within a j-tile

    // loop-invariant k fragment (B of S) for this wave's w-half
    bf16x8 bk = *(const bf16x8*)(kb + (size_t)((w0 >> 5) + kh) * 512 + h * 256 + wl * 8);

    f32x16 zero16 = {0.f,0.f,0.f,0.f,0.f,0.f,0.f,0.f,0.f,0.f,0.f,0.f,0.f,0.f,0.f,0.f};
    f32x16 acc[2];
    acc[0] = zero16; acc[1] = zero16;

    const int wbase = cq * 256 + h * 64 + kh * 32 + wl;   // within-buffer write slot
    const int rbase = kh * 512 + h * 64 + wl;             // within-buffer read base

#define QT(IT) ((const bf16x8*)(qb + (size_t)((((IT) & 31) * 4 + cq)) * 512 + qoff))
#define VG(IT, KF) ((size_t)((((IT) & 31) * 8) + kh * 4 + (KF)) * 256)

    // ---- prologue: S(0)->buf0, S(1)->buf1; vfX = vf(0); aqA/B = q tiles 2,3 ----
    bf16x8 aqA = *QT(0);
    bf16x8 aqB = *QT(1);
    uint4 vfX[4], vfY[4], vfZ[4];
#pragma unroll
    for (int kf = 0; kf < 4; kf++) vfX[kf] = vtb4[VG(0, kf)];
    {
        f32x16 s0 = __builtin_amdgcn_mfma_f32_32x32x16_bf16(aqA, bk, zero16, 0, 0, 0);
        f32x16 s1 = __builtin_amdgcn_mfma_f32_32x32x16_bf16(aqB, bk, zero16, 0, 0, 0);
        aqA = *QT(2);
        aqB = *QT(3);
        p_u4[wbase]              = exp2pkq(s0, 0);
        p_u4[wbase + 128]        = exp2pkq(s0, 8);
        p_u4[1024 + wbase]       = exp2pkq(s1, 0);
        p_u4[1024 + wbase + 128] = exp2pkq(s1, 8);
    }
    __syncthreads();

    // super-iter T: PV(2T) from RD buf-pair + vfX, PV(2T+1) + vfY;
    // S(2T+2)/S(2T+3) -> WR buf-pair; ONE barrier.
#define SUPER(T, RD, WR)                                                             \
    {                                                                                \
        const int t_ = (T);                                                          \
        _Pragma("unroll") for (int kf = 0; kf < 4; kf++) {                           \
            vfY[kf] = vtb4[VG(2 * t_ + 1, kf)];                                      \
            vfZ[kf] = vtb4[VG(2 * t_ + 2, kf)];                                      \
        }                                                                            \
        f32x16 s0 = __builtin_amdgcn_mfma_f32_32x32x16_bf16(aqA, bk, zero16, 0, 0, 0); \
        f32x16 s1 = __builtin_amdgcn_mfma_f32_32x32x16_bf16(aqB, bk, zero16, 0, 0, 0); \
        aqA = *QT(2 * t_ + 4);                                                       \
        aqB = *QT(2 * t_ + 5);                                                       \
        __builtin_amdgcn_s_setprio(1);                                               \
        _Pragma("unroll") for (int kf = 0; kf < 4; kf++) {                           \
            bf16x8 af = uint4_as_bf8(vfX[kf]);                                       \
            _Pragma("unroll") for (int nt = 0; nt < 2; nt++) {                       \
                bf16x8 bp = uint4_as_bf8(p_u4[(RD) + rbase + kf * 128 + nt * 32]);   \
                acc[nt] = __builtin_amdgcn_mfma_f32_32x32x16_bf16(af, bp, acc[nt], 0, 0, 0); \
            }                                                                        \
        }                                                                            \
        __builtin_amdgcn_s_setprio(0);                                               \
        p_u4[(WR) + wbase]       = exp2pkq(s0, 0);                                   \
        p_u4[(WR) + wbase + 128] = exp2pkq(s0, 8);                                   \
        __builtin_amdgcn_s_setprio(1);                                               \
        _Pragma("unroll") for (int kf = 0; kf < 4; kf++) {                           \
            bf16x8 af = uint4_as_bf8(vfY[kf]);                                       \
            _Pragma("unroll") for (int nt = 0; nt < 2; nt++) {                       \
                bf16x8 bp = uint4_as_bf8(p_u4[(RD) + 1024 + rbase + kf * 128 + nt * 32]); \
                acc[nt] = __builtin_amdgcn_mfma_f32_32x32x16_bf16(af, bp, acc[nt], 0, 0, 0); \
            }                                                                        \
        }                                                                            \
        __builtin_amdgcn_s_setprio(0);                                               \
        p_u4[(WR) + 1024 + wbase]       = exp2pkq(s1, 0);                            \
        p_u4[(WR) + 1024 + wbase + 128] = exp2pkq(s1, 8);                            \
        _Pragma("unroll") for (int kf = 0; kf < 4; kf++) vfX[kf] = vfZ[kf];          \
        __syncthreads();                                                             \
    }

    for (int t2 = 0; t2 < 8; t2++) {
        SUPER(2 * t2,     0,    2048);   // read bufs {0,1}, write bufs {2,3}
        SUPER(2 * t2 + 1, 2048, 0);      // read bufs {2,3}, write bufs {0,1}
    }
#undef SUPER
#undef QT
#undef VG

    // ---- epilogue: sum j-half pairs, then coalesced store (red aliases p_u4) ----
    // acc C layout: row c = cq*32 + (r&3)+8*(r>>2)+4h, col w = nt*32 + wl
#define CROW(r) (cq * 32 + ((r) & 3) + 8 * ((r) >> 2) + 4 * h)
    if (kh == 1) {
#pragma unroll
        for (int nt = 0; nt < 2; nt++)
#pragma unroll
            for (int r = 0; r < 16; r++)
                red[CROW(r) * 68 + nt * 32 + wl] = acc[nt][r];
    }
    __syncthreads();
    if (kh == 0) {
#pragma unroll
        for (int nt = 0; nt < 2; nt++)
#pragma unroll
            for (int r = 0; r < 16; r++) {
                int o = CROW(r) * 68 + nt * 32 + wl;
                red[o] += acc[nt][r];
            }
    }
#undef CROW
    __syncthreads();

    // coalesced store: out = red + x   (2048 float4 slots / 512 thr)
#pragma unroll
    for (int u = 0; u < 4; u++) {
        int k = tid + 512 * u;
        int c = k >> 4, wseg = (k & 15) * 4;
        size_t gidx = (size_t)(b * C_ + c) * W_ + w0 + wseg;
        float4 xv = *(const float4*)(x + gidx);
        const float* sp = &red[c * 68 + wseg];
        *(float4*)(out + gidx) = make_float4(sp[0] + xv.x, sp[1] + xv.y, sp[2] + xv.z, sp[3] + xv.w);
    }
}

extern "C" void kernel_launch(void* const* d_in, const int* in_sizes, int n_in,
                              void* d_out, int out_size, void* d_ws, size_t ws_size,
                              hipStream_t stream)
{
    const float* x  = (const float*)d_in[0];
    const float* Wq = (const float*)d_in[1];
    const float* bq = (const float*)d_in[2];
    const float* Wk = (const float*)d_in[3];
    const float* bk = (const float*)d_in[4];
    const float* Wv = (const float*)d_in[5];
    const float* bv = (const float*)d_in[6];
    float* out = (float*)d_out;

    unsigned short* qws2 = (unsigned short*)d_ws;        // [B][128][2][32][8] = 1MB
    unsigned short* kws2 = qws2 + (size_t)524288;        // 1MB
    unsigned short* vws2 = kws2 + (size_t)524288;        // [B][128][2][2][128][8] = 8.4MB
    float* rlp = (float*)(vws2 + (size_t)4194304);       // [4][B][W] partial l-sums

    proj<<<1024, 256, 0, stream>>>(x, Wq, Wk, Wv, bq, bk, bv, qws2, kws2, vws2);
    row_stats<<<1024, 256, 0, stream>>>(qws2, kws2, rlp);
    vscale<<<2048, 256, 0, stream>>>(vws2, rlp);
    attn_out<<<512, 512, 0, stream>>>(x, qws2, kws2, vws2, out);
}

// Round 9
// 158.671 us; speedup vs baseline: 1.0284x; 1.0284x over previous
//
#include <hip/hip_runtime.h>

#define B_ 8
#define C_ 128
#define W_ 4096
#define D_ 16
// D^-0.5 * log2(e): folded into Wq/bq; exp2 domain (v_exp_f32)
#define SCALE2 0.3606737602222409f

typedef short bf16x8 __attribute__((ext_vector_type(8)));
typedef float f32x4 __attribute__((ext_vector_type(4)));
typedef float f32x16 __attribute__((ext_vector_type(16)));

__device__ __forceinline__ unsigned short f2bf(float f) {
    unsigned int u = __float_as_uint(f);
    u += 0x7fffu + ((u >> 16) & 1u);
    return (unsigned short)(u >> 16);
}
__device__ __forceinline__ float bf2f(unsigned short h) {
    return __uint_as_float(((unsigned int)h) << 16);
}
// pack two f32 -> u32 of 2 bf16 (TRUNCATED) in ONE v_perm_b32
__device__ __forceinline__ unsigned int pk2bf(float lo, float hi) {
    return __builtin_amdgcn_perm(__float_as_uint(hi), __float_as_uint(lo), 0x07060302u);
}
__device__ __forceinline__ bf16x8 uint4_as_bf8(uint4 u) {
    union { uint4 u; bf16x8 v; } t;
    t.u = u;
    return t.v;
}
// exp2 8 S-values (C-regs r0..r0+7) -> one K=16 fragment as uint4
__device__ __forceinline__ uint4 exp2pkq(f32x16 s, int r0) {
    return make_uint4(
        pk2bf(__builtin_amdgcn_exp2f(s[r0+0]), __builtin_amdgcn_exp2f(s[r0+1])),
        pk2bf(__builtin_amdgcn_exp2f(s[r0+2]), __builtin_amdgcn_exp2f(s[r0+3])),
        pk2bf(__builtin_amdgcn_exp2f(s[r0+4]), __builtin_amdgcn_exp2f(s[r0+5])),
        pk2bf(__builtin_amdgcn_exp2f(s[r0+6]), __builtin_amdgcn_exp2f(s[r0+7])));
}
// LDS chunk swizzle for proj staging
__device__ __forceinline__ int xswz(int j, int c8) {
    return c8 ^ (j & 7) ^ ((j >> 3) & 7);
}

// ---------------- prep: Wv -> bf16; [Wq*SCALE2 ; Wk] -> bf16 ----------------
// One-time weight conversion. Keep as a kernel: inlining it into proj re-converts
// weights in EVERY block (1024x redundant VALU) and measured slower (R7).
__global__ __launch_bounds__(256) void prep(
    const float* __restrict__ Wq, const float* __restrict__ Wk, const float* __restrict__ Wv,
    unsigned short* __restrict__ Wvbf, unsigned short* __restrict__ Wqkbf)
{
    int g = blockIdx.x * 256 + threadIdx.x;
    const float* src; unsigned short* dst; float sc = 1.0f;
    if (g < 4096)      { src = Wv + g * 4;            dst = Wvbf + g * 4; }
    else if (g < 4608) { int t = g - 4096; src = Wq + t * 4; dst = Wqkbf + t * 4; sc = SCALE2; }
    else               { int t = g - 4608; src = Wk + t * 4; dst = Wqkbf + 2048 + t * 4; }
    float4 v = *(const float4*)src;
    unsigned short h[4] = {f2bf(v.x * sc), f2bf(v.y * sc), f2bf(v.z * sc), f2bf(v.w * sc)};
    *(ushort4*)dst = *(ushort4*)h;
}

// ---------------- proj: q,k,v in one pass; frag-major outputs ----------------
// qws2/kws2: [b][pos/32][h 0-1][pos%32][8 dims]  (dims h*8+i; K=16, no padding)
// vws2:      [b][jt][kf 0-1][h 0-1][c 128][8]    slot i -> j = jt*32 + kf*16+4h+(i&3)+8*(i>>2)
__global__ __launch_bounds__(256) void proj(
    const float* __restrict__ x, const unsigned short* __restrict__ Wvbf,
    const unsigned short* __restrict__ Wqkbf,
    const float* __restrict__ bqp, const float* __restrict__ bkp, const float* __restrict__ bvp,
    unsigned short* __restrict__ qws2, unsigned short* __restrict__ kws2,
    unsigned short* __restrict__ vws2)
{
    __shared__ unsigned short xbf[32 * 128];     // [j][c] swizzled chunks, 8KB
    __shared__ unsigned short outs[128 * 36];    // v bounce [c][j], 9KB
    __shared__ unsigned short qk_s[2][32][24];   // q/k bounce [qk][pos][dim], 3KB (row 48B)

    int b  = blockIdx.x & 7;
    int j0 = (blockIdx.x >> 3) * 32;
    int jt = j0 >> 5;
    int tid = threadIdx.x;
    int wid = tid >> 6, lane = tid & 63, n = lane & 15, q4 = lane >> 4;

    // stage x tile [128c][32j] -> bf16 LDS [j][c] swizzled; c-paired v_perm packs
    {
        unsigned int* xbf32 = (unsigned int*)xbf;
#pragma unroll
        for (int i = 0; i < 8; i++) {
            int p = tid + 256 * i;            // 2048 c-pair slots
            int c2 = p >> 5;                  // c = 2*c2, 2*c2+1
            int j  = p & 31;
            const float* xp = x + (size_t)(b * C_ + 2 * c2) * W_ + j0 + j;
            float lo = xp[0];
            float hi = xp[W_];
            xbf32[j * 64 + xswz(j, c2 >> 2) * 4 + (c2 & 3)] = pk2bf(lo, hi);
        }
    }
    __syncthreads();

    const f32x4 zero = {0.f, 0.f, 0.f, 0.f};
    f32x4 accv[2][2]; f32x4 accqk = zero;
#pragma unroll
    for (int os = 0; os < 2; os++)
#pragma unroll
        for (int js = 0; js < 2; js++) accv[os][js] = zero;

    int isK = wid >> 1;          // waves 0,1: q; waves 2,3: k
    int jsm = wid & 1;           // which j-tile this wave's q/k MFMA covers

#pragma unroll
    for (int kk = 0; kk < 128; kk += 32) {
        bf16x8 av[2], aqkf, bx[2];
#pragma unroll
        for (int os = 0; os < 2; os++)
            av[os] = *(const bf16x8*)(Wvbf + (wid * 32 + os * 16 + n) * 128 + kk + q4 * 8);
        aqkf = *(const bf16x8*)(Wqkbf + (isK * 16 + n) * 128 + kk + q4 * 8);
#pragma unroll
        for (int js = 0; js < 2; js++) {
            int j = js * 16 + n;
            bx[js] = *(const bf16x8*)&xbf[j * 128 + xswz(j, (kk >> 3) + q4) * 8];
        }
#pragma unroll
        for (int os = 0; os < 2; os++)
#pragma unroll
            for (int js = 0; js < 2; js++)
                accv[os][js] = __builtin_amdgcn_mfma_f32_16x16x32_bf16(av[os], bx[js], accv[os][js], 0, 0, 0);
        accqk = __builtin_amdgcn_mfma_f32_16x16x32_bf16(aqkf, bx[jsm], accqk, 0, 0, 0);
    }

    // q/k epilogue -> qk_s (C layout: row d = q4*4+r, col pos = jsm*16+n)
    {
        int pos = jsm * 16 + n;
        const float* bias = isK ? bkp : bqp;
        float bsc = isK ? 1.0f : SCALE2;
#pragma unroll
        for (int r = 0; r < 4; r++)
            qk_s[isK][pos][q4 * 4 + r] = f2bf(accqk[r] + bias[q4 * 4 + r] * bsc);
    }

    // v epilogue -> outs [c][j]
    float bvv[2][4];
#pragma unroll
    for (int os = 0; os < 2; os++)
#pragma unroll
        for (int r = 0; r < 4; r++) bvv[os][r] = bvp[wid * 32 + os * 16 + q4 * 4 + r];
#pragma unroll
    for (int os = 0; os < 2; os++)
#pragma unroll
        for (int js = 0; js < 2; js++)
#pragma unroll
            for (int r = 0; r < 4; r++) {
                int c = wid * 32 + os * 16 + q4 * 4 + r;
                int j = js * 16 + n;
                outs[c * 36 + j] = f2bf(accv[os][js][r] + bvv[os][r]);
            }
    __syncthreads();

    // qws2/kws2 writers (128 tasks x 16B)
    if (tid < 128) {
        int qk = tid >> 6, hh = (tid >> 5) & 1, jl = tid & 31;
        uint4 v = *(const uint4*)&qk_s[qk][jl][hh * 8];
        unsigned short* dst = (qk ? kws2 : qws2)
            + (size_t)(b * 128 + jt) * 512 + hh * 256 + jl * 8;
        *(uint4*)dst = v;
    }
    // vws2 writers (512 tasks x 16B): slot i -> j = kf*16+4h+{0..3,8..11}
#pragma unroll
    for (int rep = 0; rep < 2; rep++) {
        int t = tid + rep * 256;
        int c = t & 127, sel = t >> 7;          // sel = kf*2+h
        int jb = (sel >> 1) * 16 + (sel & 1) * 4;
        uint2 lo = *(const uint2*)&outs[c * 36 + jb];
        uint2 hi = *(const uint2*)&outs[c * 36 + jb + 8];
        *(uint4*)(vws2 + ((size_t)(b * 128 + jt) * 4 + sel) * 1024 + c * 8) =
            make_uint4(lo.x, lo.y, hi.x, hi.y);
    }
}

// ---------------- row_stats: partial l-sums via 32x32x16, w split 4 ways ----------------
// rlp[wsp][b][W] = sum over w-quarter of exp2(s2[j,w])
__global__ __launch_bounds__(256) void row_stats(
    const unsigned short* __restrict__ qws2, const unsigned short* __restrict__ kws2,
    float* __restrict__ rlp)
{
    int blk = blockIdx.x;                // grid 1024
    int b = blk & 7;
    int j0 = ((blk >> 3) & 31) * 128;
    int wsp = blk >> 8;                  // 0..3
    int tid = threadIdx.x;
    int wid = tid >> 6, lane = tid & 63, wl = lane & 31, h = lane >> 5;

    const unsigned short* qb = qws2 + (size_t)b * 65536;
    const unsigned short* kb = kws2 + (size_t)b * 65536;
    int jt = (j0 >> 5) + wid;

    bf16x8 aq = *(const bf16x8*)(qb + (size_t)jt * 512 + h * 256 + wl * 8);
    f32x16 zero16 = {0.f,0.f,0.f,0.f,0.f,0.f,0.f,0.f,0.f,0.f,0.f,0.f,0.f,0.f,0.f,0.f};

    float lt[16];
#pragma unroll
    for (int r = 0; r < 16; r++) lt[r] = 0.f;

    bf16x8 bkc = *(const bf16x8*)(kb + (size_t)(wsp * 32) * 512 + h * 256 + wl * 8);
    for (int t = 0; t < 32; t++) {
        f32x16 s = __builtin_amdgcn_mfma_f32_32x32x16_bf16(aq, bkc, zero16, 0, 0, 0);
        int tn = wsp * 32 + ((t + 1) & 31);   // branchless wrap prefetch
        bkc = *(const bf16x8*)(kb + (size_t)tn * 512 + h * 256 + wl * 8);
#pragma unroll
        for (int r = 0; r < 16; r++) lt[r] += __builtin_amdgcn_exp2f(s[r]);
    }
    // reduce over 32 w-lanes (same half)
#pragma unroll
    for (int mask = 1; mask < 32; mask <<= 1)
#pragma unroll
        for (int r = 0; r < 16; r++) lt[r] += __shfl_xor(lt[r], mask, 64);
    if (wl == 0) {
        // C rows: r=4g+e -> j-local = e + 8g + 4h
#pragma unroll
        for (int g = 0; g < 4; g++) {
            f32x4 v = {lt[4*g+0], lt[4*g+1], lt[4*g+2], lt[4*g+3]};
            *(f32x4*)(rlp + (size_t)wsp * 32768 + (size_t)b * W_ + j0 + wid * 32 + 4 * h + 8 * g) = v;
        }
    }
}

// ---------------- vscale: v' = v * (1/l), finl inlined (rls never hits global) ----------------
// Block bi covers g = bi*256..+255 (16B units); kf/jt/b constant per block ->
// exactly 16 j rows. 16 threads sum the 4 rlp partials + invert into LDS.
__global__ __launch_bounds__(256) void vscale(unsigned short* __restrict__ vws2,
                                              const float* __restrict__ rlp)
{
    __shared__ float rl[16];
    int bi = blockIdx.x;                 // 0..2047
    int g0 = bi * 256;
    int kf = (g0 >> 8) & 1, jt = (g0 >> 9) & 127, b = g0 >> 16;
    int tid = threadIdx.x;
    if (tid < 16) {
        int idx = b * W_ + jt * 32 + kf * 16 + tid;
        float l = rlp[idx] + rlp[32768 + idx] + rlp[65536 + idx] + rlp[98304 + idx];
        rl[tid] = 1.0f / l;
    }
    __syncthreads();

    int g = g0 + tid;
    int hh = (g >> 7) & 1;
    float4 r0 = *(const float4*)&rl[4 * hh];        // slots 0-3: j = kf*16+4hh+{0..3}
    float4 r1 = *(const float4*)&rl[4 * hh + 8];    // slots 4-7: j = kf*16+4hh+8+{0..3}
    uint4 v = *(const uint4*)(vws2 + (size_t)g * 8);
    unsigned int o0 = pk2bf(bf2f((unsigned short)(v.x & 0xffffu)) * r0.x,
                            bf2f((unsigned short)(v.x >> 16))     * r0.y);
    unsigned int o1 = pk2bf(bf2f((unsigned short)(v.y & 0xffffu)) * r0.z,
                            bf2f((unsigned short)(v.y >> 16))     * r0.w);
    unsigned int o2 = pk2bf(bf2f((unsigned short)(v.z & 0xffffu)) * r1.x,
                            bf2f((unsigned short)(v.z >> 16))     * r1.y);
    unsigned int o3 = pk2bf(bf2f((unsigned short)(v.w & 0xffffu)) * r1.z,
                            bf2f((unsigned short)(v.w >> 16))     * r1.w);
    *(uint4*)(vws2 + (size_t)g * 8) = make_uint4(o0, o1, o2, o3);
}

// ---------------- attn_out: 8-wave LDS-shared-P pipeline (round-2 proven best) ----------------
// Block: 512 thr, tile 128c x 64w, j-step 128 per iter (32 iters).
// Wave (cq=wid>>1, kh=wid&1):
//   S phase: one 32x32 S subtile -> exp2 -> 2 uint4 to LDS p-tile (identity-lane slots).
//   PV phase: c-quarter cq, j-half kh (4 of 8 kf chunks): acc[2] f32x16.
// Sync: plain __syncthreads() per iter. Confirmed regressions — do NOT re-add:
//   * inline-asm no-drain barrier (raced under graph replay, and slower)
//   * rlog fold into S phase (+13us: serializes on the pre-barrier chain)
//   * c-split 4-wave blocks (S duplication +VALU, occupancy unchanged)
//   * 4-buffer one-barrier-per-2-steps (vf 3-deep spills: +8MB scratch writes, +5us)
__global__ __launch_bounds__(512, 4) void attn_out(
    const float* __restrict__ x, const unsigned short* __restrict__ qws2,
    const unsigned short* __restrict__ kws2, const unsigned short* __restrict__ vws2,
    float* __restrict__ out)
{
    // p_lds slot: kf_g*128 + h*64 + wh*32 + wl  (uint4 units), kf_g = 16-j chunk 0..7
    __shared__ uint4 p_lds[2][1024];     // 32 KB, double-buffered P
    __shared__ float red[128 * 68];      // 34.8 KB, pair-reduce + store bounce

    int b  = blockIdx.x & 7;
    int w0 = (blockIdx.x >> 3) * 64;
    int tid = threadIdx.x;
    int wid = tid >> 6, lane = tid & 63, wl = lane & 31, h = lane >> 5;
    int cq = wid >> 1, kh = wid & 1;

    const unsigned short* qb  = qws2 + (size_t)b * 65536;
    const unsigned short* kb  = kws2 + (size_t)b * 65536;
    const uint4* vtb4 = (const uint4*)(vws2 + (size_t)b * 524288) + h * 128 + (cq * 32 + wl);
    const int qoff = h * 256 + wl * 8;   // short units within a j-tile

    // loop-invariant k fragment (B of S) for this wave's w-half
    bf16x8 bk = *(const bf16x8*)(kb + (size_t)((w0 >> 5) + kh) * 512 + h * 256 + wl * 8);

    f32x16 zero16 = {0.f,0.f,0.f,0.f,0.f,0.f,0.f,0.f,0.f,0.f,0.f,0.f,0.f,0.f,0.f,0.f};
    f32x16 acc[2];
    acc[0] = zero16; acc[1] = zero16;

    const int wbase = cq * 256 + h * 64 + kh * 32 + wl;   // write slot (kfl=0); +128 kfl=1
    const int rbase = kh * 512 + h * 64 + wl;             // read base; +kf*128 +nt*32

    // ---- prologue: S(0) -> p[0]; vfA(0); aq(1) ----
    bf16x8 aq = *(const bf16x8*)(qb + (size_t)cq * 512 + qoff);
    uint4 vfA[4], vfB[4];
#pragma unroll
    for (int kf = 0; kf < 4; kf++)
        vfA[kf] = vtb4[(size_t)(kh * 4 + kf) * 256];
    {
        f32x16 s = __builtin_amdgcn_mfma_f32_32x32x16_bf16(aq, bk, zero16, 0, 0, 0);
        aq = *(const bf16x8*)(qb + (size_t)(4 + cq) * 512 + qoff);
        p_lds[0][wbase]       = exp2pkq(s, 0);
        p_lds[0][wbase + 128] = exp2pkq(s, 8);
    }
    __syncthreads();

    // iter it: PV from p[it&1] + vf(it); S(it+1)+exp2 -> p[(it+1)&1]
#define STEP(IT, CUR, VC, VN)                                                        \
    {                                                                                \
        const int it_ = (IT);                                                        \
        int kgb = ((it_ + 1) & 31) * 8 + kh * 4;                                     \
        _Pragma("unroll") for (int kf = 0; kf < 4; kf++)                             \
            VN[kf] = vtb4[(size_t)(kgb + kf) * 256];                                 \
        f32x16 s = __builtin_amdgcn_mfma_f32_32x32x16_bf16(aq, bk, zero16, 0, 0, 0); \
        aq = *(const bf16x8*)(qb + (size_t)(((it_ + 2) & 31) * 4 + cq) * 512 + qoff);\
        __builtin_amdgcn_s_setprio(1);                                               \
        _Pragma("unroll") for (int kf = 0; kf < 4; kf++) {                           \
            bf16x8 af = uint4_as_bf8(VC[kf]);                                        \
            _Pragma("unroll") for (int nt = 0; nt < 2; nt++) {                       \
                bf16x8 bp = uint4_as_bf8(p_lds[CUR][rbase + kf * 128 + nt * 32]);    \
                acc[nt] = __builtin_amdgcn_mfma_f32_32x32x16_bf16(af, bp, acc[nt], 0, 0, 0); \
            }                                                                        \
        }                                                                            \
        __builtin_amdgcn_s_setprio(0);                                               \
        p_lds[(CUR) ^ 1][wbase]       = exp2pkq(s, 0);                               \
        p_lds[(CUR) ^ 1][wbase + 128] = exp2pkq(s, 8);                               \
        __syncthreads();                                                             \
    }

    for (int i2 = 0; i2 < 16; i2++) {
        STEP(2 * i2,     0, vfA, vfB);
        STEP(2 * i2 + 1, 1, vfB, vfA);
    }
#undef STEP

    // ---- epilogue: sum j-half pairs, then coalesced store ----
    // acc C layout: row c = cq*32 + (r&3)+8*(r>>2)+4h, col w = nt*32 + wl
#define CROW(r) (cq * 32 + ((r) & 3) + 8 * ((r) >> 2) + 4 * h)
    if (kh == 1) {
#pragma unroll
        for (int nt = 0; nt < 2; nt++)
#pragma unroll
            for (int r = 0; r < 16; r++)
                red[CROW(r) * 68 + nt * 32 + wl] = acc[nt][r];
    }
    __syncthreads();
    if (kh == 0) {
#pragma unroll
        for (int nt = 0; nt < 2; nt++)
#pragma unroll
            for (int r = 0; r < 16; r++) {
                int o = CROW(r) * 68 + nt * 32 + wl;
                red[o] += acc[nt][r];
            }
    }
#undef CROW
    __syncthreads();

    // coalesced store: out = red + x   (2048 float4 slots / 512 thr)
#pragma unroll
    for (int u = 0; u < 4; u++) {
        int k = tid + 512 * u;
        int c = k >> 4, wseg = (k & 15) * 4;
        size_t gidx = (size_t)(b * C_ + c) * W_ + w0 + wseg;
        float4 xv = *(const float4*)(x + gidx);
        const float* sp = &red[c * 68 + wseg];
        *(float4*)(out + gidx) = make_float4(sp[0] + xv.x, sp[1] + xv.y, sp[2] + xv.z, sp[3] + xv.w);
    }
}

extern "C" void kernel_launch(void* const* d_in, const int* in_sizes, int n_in,
                              void* d_out, int out_size, void* d_ws, size_t ws_size,
                              hipStream_t stream)
{
    const float* x  = (const float*)d_in[0];
    const float* Wq = (const float*)d_in[1];
    const float* bq = (const float*)d_in[2];
    const float* Wk = (const float*)d_in[3];
    const float* bk = (const float*)d_in[4];
    const float* Wv = (const float*)d_in[5];
    const float* bv = (const float*)d_in[6];
    float* out = (float*)d_out;

    unsigned short* qws2 = (unsigned short*)d_ws;        // [B][128][2][32][8] = 1MB
    unsigned short* kws2 = qws2 + (size_t)524288;        // 1MB
    unsigned short* vws2 = kws2 + (size_t)524288;        // [B][128][2][2][128][8] = 8.4MB
    unsigned short* Wvbf = vws2 + (size_t)4194304;       // [128][128]
    unsigned short* Wqkbf = Wvbf + 16384;                // [32][128]
    float* rlp = (float*)(Wqkbf + 4096);                 // [4][B][W] partial l-sums

    prep<<<20, 256, 0, stream>>>(Wq, Wk, Wv, Wvbf, Wqkbf);
    proj<<<1024, 256, 0, stream>>>(x, Wvbf, Wqkbf, bq, bk, bv, qws2, kws2, vws2);
    row_stats<<<1024, 256, 0, stream>>>(qws2, kws2, rlp);
    vscale<<<2048, 256, 0, stream>>>(vws2, rlp);
    attn_out<<<512, 512, 0, stream>>>(x, qws2, kws2, vws2, out);
}

// Round 10
// 152.402 us; speedup vs baseline: 1.0707x; 1.0411x over previous
//
#include <hip/hip_runtime.h>

#define B_ 8
#define C_ 128
#define W_ 4096
#define D_ 16
// D^-0.5 * log2(e): folded into Wq/bq; exp2 domain (v_exp_f32)
#define SCALE2 0.3606737602222409f

typedef short bf16x8 __attribute__((ext_vector_type(8)));
typedef float f32x4 __attribute__((ext_vector_type(4)));
typedef float f32x16 __attribute__((ext_vector_type(16)));

__device__ __forceinline__ unsigned short f2bf(float f) {
    unsigned int u = __float_as_uint(f);
    u += 0x7fffu + ((u >> 16) & 1u);
    return (unsigned short)(u >> 16);
}
__device__ __forceinline__ float bf2f(unsigned short h) {
    return __uint_as_float(((unsigned int)h) << 16);
}
// pack two f32 -> u32 of 2 bf16 (TRUNCATED) in ONE v_perm_b32
__device__ __forceinline__ unsigned int pk2bf(float lo, float hi) {
    return __builtin_amdgcn_perm(__float_as_uint(hi), __float_as_uint(lo), 0x07060302u);
}
__device__ __forceinline__ bf16x8 uint4_as_bf8(uint4 u) {
    union { uint4 u; bf16x8 v; } t;
    t.u = u;
    return t.v;
}
// exp2 8 S-values (C-regs r0..r0+7) -> one K=16 fragment as uint4
__device__ __forceinline__ uint4 exp2pkq(f32x16 s, int r0) {
    return make_uint4(
        pk2bf(__builtin_amdgcn_exp2f(s[r0+0]), __builtin_amdgcn_exp2f(s[r0+1])),
        pk2bf(__builtin_amdgcn_exp2f(s[r0+2]), __builtin_amdgcn_exp2f(s[r0+3])),
        pk2bf(__builtin_amdgcn_exp2f(s[r0+4]), __builtin_amdgcn_exp2f(s[r0+5])),
        pk2bf(__builtin_amdgcn_exp2f(s[r0+6]), __builtin_amdgcn_exp2f(s[r0+7])));
}
// LDS chunk swizzle for proj staging
__device__ __forceinline__ int xswz(int j, int c8) {
    return c8 ^ (j & 7) ^ ((j >> 3) & 7);
}

// ---------------- prep: Wv -> bf16; [Wq*SCALE2 ; Wk] -> bf16 ----------------
// One-time weight conversion. Keep as a kernel: inlining into proj re-converts
// per block (1024x redundant VALU) and measured slower (R7).
__global__ __launch_bounds__(256) void prep(
    const float* __restrict__ Wq, const float* __restrict__ Wk, const float* __restrict__ Wv,
    unsigned short* __restrict__ Wvbf, unsigned short* __restrict__ Wqkbf)
{
    int g = blockIdx.x * 256 + threadIdx.x;
    const float* src; unsigned short* dst; float sc = 1.0f;
    if (g < 4096)      { src = Wv + g * 4;            dst = Wvbf + g * 4; }
    else if (g < 4608) { int t = g - 4096; src = Wq + t * 4; dst = Wqkbf + t * 4; sc = SCALE2; }
    else               { int t = g - 4608; src = Wk + t * 4; dst = Wqkbf + 2048 + t * 4; }
    float4 v = *(const float4*)src;
    unsigned short h[4] = {f2bf(v.x * sc), f2bf(v.y * sc), f2bf(v.z * sc), f2bf(v.w * sc)};
    *(ushort4*)dst = *(ushort4*)h;
}

// ---------------- proj: q,k,v in one pass; frag-major outputs ----------------
// qws2/kws2: [b][pos/32][h 0-1][pos%32][8 dims]  (dims h*8+i; K=16, no padding)
// vws2:      [b][jt][kf 0-1][h 0-1][c 128][8]    slot i -> j = jt*32 + kf*16+4h+(i&3)+8*(i>>2)
__global__ __launch_bounds__(256) void proj(
    const float* __restrict__ x, const unsigned short* __restrict__ Wvbf,
    const unsigned short* __restrict__ Wqkbf,
    const float* __restrict__ bqp, const float* __restrict__ bkp, const float* __restrict__ bvp,
    unsigned short* __restrict__ qws2, unsigned short* __restrict__ kws2,
    unsigned short* __restrict__ vws2)
{
    __shared__ unsigned short xbf[32 * 128];     // [j][c] swizzled chunks, 8KB
    __shared__ unsigned short outs[128 * 36];    // v bounce [c][j], 9KB
    __shared__ unsigned short qk_s[2][32][24];   // q/k bounce [qk][pos][dim], 3KB (row 48B)

    int b  = blockIdx.x & 7;
    int j0 = (blockIdx.x >> 3) * 32;
    int jt = j0 >> 5;
    int tid = threadIdx.x;
    int wid = tid >> 6, lane = tid & 63, n = lane & 15, q4 = lane >> 4;

    // stage x tile [128c][32j] -> bf16 LDS [j][c] swizzled; c-paired v_perm packs
    {
        unsigned int* xbf32 = (unsigned int*)xbf;
#pragma unroll
        for (int i = 0; i < 8; i++) {
            int p = tid + 256 * i;            // 2048 c-pair slots
            int c2 = p >> 5;                  // c = 2*c2, 2*c2+1
            int j  = p & 31;
            const float* xp = x + (size_t)(b * C_ + 2 * c2) * W_ + j0 + j;
            float lo = xp[0];
            float hi = xp[W_];
            xbf32[j * 64 + xswz(j, c2 >> 2) * 4 + (c2 & 3)] = pk2bf(lo, hi);
        }
    }
    __syncthreads();

    const f32x4 zero = {0.f, 0.f, 0.f, 0.f};
    f32x4 accv[2][2]; f32x4 accqk = zero;
#pragma unroll
    for (int os = 0; os < 2; os++)
#pragma unroll
        for (int js = 0; js < 2; js++) accv[os][js] = zero;

    int isK = wid >> 1;          // waves 0,1: q; waves 2,3: k
    int jsm = wid & 1;           // which j-tile this wave's q/k MFMA covers

#pragma unroll
    for (int kk = 0; kk < 128; kk += 32) {
        bf16x8 av[2], aqkf, bx[2];
#pragma unroll
        for (int os = 0; os < 2; os++)
            av[os] = *(const bf16x8*)(Wvbf + (wid * 32 + os * 16 + n) * 128 + kk + q4 * 8);
        aqkf = *(const bf16x8*)(Wqkbf + (isK * 16 + n) * 128 + kk + q4 * 8);
#pragma unroll
        for (int js = 0; js < 2; js++) {
            int j = js * 16 + n;
            bx[js] = *(const bf16x8*)&xbf[j * 128 + xswz(j, (kk >> 3) + q4) * 8];
        }
#pragma unroll
        for (int os = 0; os < 2; os++)
#pragma unroll
            for (int js = 0; js < 2; js++)
                accv[os][js] = __builtin_amdgcn_mfma_f32_16x16x32_bf16(av[os], bx[js], accv[os][js], 0, 0, 0);
        accqk = __builtin_amdgcn_mfma_f32_16x16x32_bf16(aqkf, bx[jsm], accqk, 0, 0, 0);
    }

    // q/k epilogue -> qk_s (C layout: row d = q4*4+r, col pos = jsm*16+n)
    {
        int pos = jsm * 16 + n;
        const float* bias = isK ? bkp : bqp;
        float bsc = isK ? 1.0f : SCALE2;
#pragma unroll
        for (int r = 0; r < 4; r++)
            qk_s[isK][pos][q4 * 4 + r] = f2bf(accqk[r] + bias[q4 * 4 + r] * bsc);
    }

    // v epilogue -> outs [c][j]
    float bvv[2][4];
#pragma unroll
    for (int os = 0; os < 2; os++)
#pragma unroll
        for (int r = 0; r < 4; r++) bvv[os][r] = bvp[wid * 32 + os * 16 + q4 * 4 + r];
#pragma unroll
    for (int os = 0; os < 2; os++)
#pragma unroll
        for (int js = 0; js < 2; js++)
#pragma unroll
            for (int r = 0; r < 4; r++) {
                int c = wid * 32 + os * 16 + q4 * 4 + r;
                int j = js * 16 + n;
                outs[c * 36 + j] = f2bf(accv[os][js][r] + bvv[os][r]);
            }
    __syncthreads();

    // qws2/kws2 writers (128 tasks x 16B)
    if (tid < 128) {
        int qk = tid >> 6, hh = (tid >> 5) & 1, jl = tid & 31;
        uint4 v = *(const uint4*)&qk_s[qk][jl][hh * 8];
        unsigned short* dst = (qk ? kws2 : qws2)
            + (size_t)(b * 128 + jt) * 512 + hh * 256 + jl * 8;
        *(uint4*)dst = v;
    }
    // vws2 writers (512 tasks x 16B): slot i -> j = kf*16+4h+{0..3,8..11}
#pragma unroll
    for (int rep = 0; rep < 2; rep++) {
        int t = tid + rep * 256;
        int c = t & 127, sel = t >> 7;          // sel = kf*2+h
        int jb = (sel >> 1) * 16 + (sel & 1) * 4;
        uint2 lo = *(const uint2*)&outs[c * 36 + jb];
        uint2 hi = *(const uint2*)&outs[c * 36 + jb + 8];
        *(uint4*)(vws2 + ((size_t)(b * 128 + jt) * 4 + sel) * 1024 + c * 8) =
            make_uint4(lo.x, lo.y, hi.x, hi.y);
    }
}

// ---------------- rsv: row sums + v-scale fused per (b, jt) ----------------
// Grid 1024 = b*1 + jt*8 decode (b = blk&7, jt = blk>>3). Block: 4 waves.
// Wave wsp computes the partial l-sum of w-quarter wsp for the SAME 32 j rows
// (identical MFMA/exp2 count as the old row_stats), reduces into LDS; then
// 1/l is computed in LDS and the block scales its own 8 KB vws2 slice
// in place. Deletes the vscale kernel AND the rlp global round-trip.
__global__ __launch_bounds__(256) void rsv(
    const unsigned short* __restrict__ qws2, const unsigned short* __restrict__ kws2,
    unsigned short* __restrict__ vws2)
{
    __shared__ float lsum[4][32];
    __shared__ float rl[32];

    int blk = blockIdx.x;                // 1024
    int b  = blk & 7;
    int jt = blk >> 3;                   // 0..127
    int tid = threadIdx.x;
    int wsp = tid >> 6, lane = tid & 63, wl = lane & 31, h = lane >> 5;

    const unsigned short* qb = qws2 + (size_t)b * 65536;
    const unsigned short* kb = kws2 + (size_t)b * 65536;

    bf16x8 aq = *(const bf16x8*)(qb + (size_t)jt * 512 + h * 256 + wl * 8);
    f32x16 zero16 = {0.f,0.f,0.f,0.f,0.f,0.f,0.f,0.f,0.f,0.f,0.f,0.f,0.f,0.f,0.f,0.f};

    float lt[16];
#pragma unroll
    for (int r = 0; r < 16; r++) lt[r] = 0.f;

    bf16x8 bkc = *(const bf16x8*)(kb + (size_t)(wsp * 32) * 512 + h * 256 + wl * 8);
    for (int t = 0; t < 32; t++) {
        f32x16 s = __builtin_amdgcn_mfma_f32_32x32x16_bf16(aq, bkc, zero16, 0, 0, 0);
        int tn = wsp * 32 + ((t + 1) & 31);   // branchless wrap prefetch
        bkc = *(const bf16x8*)(kb + (size_t)tn * 512 + h * 256 + wl * 8);
#pragma unroll
        for (int r = 0; r < 16; r++) lt[r] += __builtin_amdgcn_exp2f(s[r]);
    }
    // reduce over 32 w-lanes (same half)
#pragma unroll
    for (int mask = 1; mask < 32; mask <<= 1)
#pragma unroll
        for (int r = 0; r < 16; r++) lt[r] += __shfl_xor(lt[r], mask, 64);
    if (wl == 0) {
        // C rows: r=4g+e -> j-local = e + 8g + 4h
#pragma unroll
        for (int g = 0; g < 4; g++) {
            f32x4 v = {lt[4*g+0], lt[4*g+1], lt[4*g+2], lt[4*g+3]};
            *(f32x4*)&lsum[wsp][4 * h + 8 * g] = v;
        }
    }
    __syncthreads();
    if (tid < 32)
        rl[tid] = 1.0f / (lsum[0][tid] + lsum[1][tid] + lsum[2][tid] + lsum[3][tid]);
    __syncthreads();

    // scale the 512 uint4 units of this jt slice (2 per thread)
    // unit u: c = u&127, sel = u>>7 (= kf*2+h); slot i -> j = kf*16+4h+(i&3)+8*(i>>2)
#pragma unroll
    for (int rep = 0; rep < 2; rep++) {
        int u = tid + rep * 256;
        int c = u & 127, sel = u >> 7;
        int jb = (sel >> 1) * 16 + (sel & 1) * 4;
        float4 r0 = *(const float4*)&rl[jb];        // slots 0-3
        float4 r1 = *(const float4*)&rl[jb + 8];    // slots 4-7
        unsigned short* vp = vws2 + ((size_t)(b * 128 + jt) * 4 + sel) * 1024 + c * 8;
        uint4 v = *(const uint4*)vp;
        unsigned int o0 = pk2bf(bf2f((unsigned short)(v.x & 0xffffu)) * r0.x,
                                bf2f((unsigned short)(v.x >> 16))     * r0.y);
        unsigned int o1 = pk2bf(bf2f((unsigned short)(v.y & 0xffffu)) * r0.z,
                                bf2f((unsigned short)(v.y >> 16))     * r0.w);
        unsigned int o2 = pk2bf(bf2f((unsigned short)(v.z & 0xffffu)) * r1.x,
                                bf2f((unsigned short)(v.z >> 16))     * r1.y);
        unsigned int o3 = pk2bf(bf2f((unsigned short)(v.w & 0xffffu)) * r1.z,
                                bf2f((unsigned short)(v.w >> 16))     * r1.w);
        *(uint4*)vp = make_uint4(o0, o1, o2, o3);
    }
}

// ---------------- attn_out: 8-wave LDS-shared-P pipeline (round-2 proven best) ----------------
// Block: 512 thr, tile 128c x 64w, j-step 128 per iter (32 iters).
// Wave (cq=wid>>1, kh=wid&1):
//   S phase: one 32x32 S subtile -> exp2 -> 2 uint4 to LDS p-tile (identity-lane slots).
//   PV phase: c-quarter cq, j-half kh (4 of 8 kf chunks): acc[2] f32x16.
// Sync: plain __syncthreads() per iter. Confirmed regressions — do NOT re-add:
//   * inline-asm no-drain barrier (raced under graph replay, and slower)
//   * rlog fold into S phase (+13us: serializes on the pre-barrier chain)
//   * c-split 4-wave blocks (S duplication +VALU, occupancy unchanged)
//   * 4-buffer one-barrier-per-2-steps (vf 3-deep spills: +8MB scratch writes, +5us)
__global__ __launch_bounds__(512, 4) void attn_out(
    const float* __restrict__ x, const unsigned short* __restrict__ qws2,
    const unsigned short* __restrict__ kws2, const unsigned short* __restrict__ vws2,
    float* __restrict__ out)
{
    // p_lds slot: kf_g*128 + h*64 + wh*32 + wl  (uint4 units), kf_g = 16-j chunk 0..7
    __shared__ uint4 p_lds[2][1024];     // 32 KB, double-buffered P
    __shared__ float red[128 * 68];      // 34.8 KB, pair-reduce + store bounce

    int b  = blockIdx.x & 7;
    int w0 = (blockIdx.x >> 3) * 64;
    int tid = threadIdx.x;
    int wid = tid >> 6, lane = tid & 63, wl = lane & 31, h = lane >> 5;
    int cq = wid >> 1, kh = wid & 1;

    const unsigned short* qb  = qws2 + (size_t)b * 65536;
    const unsigned short* kb  = kws2 + (size_t)b * 65536;
    const uint4* vtb4 = (const uint4*)(vws2 + (size_t)b * 524288) + h * 128 + (cq * 32 + wl);
    const int qoff = h * 256 + wl * 8;   // short units within a j-tile

    // loop-invariant k fragment (B of S) for this wave's w-half
    bf16x8 bk = *(const bf16x8*)(kb + (size_t)((w0 >> 5) + kh) * 512 + h * 256 + wl * 8);

    f32x16 zero16 = {0.f,0.f,0.f,0.f,0.f,0.f,0.f,0.f,0.f,0.f,0.f,0.f,0.f,0.f,0.f,0.f};
    f32x16 acc[2];
    acc[0] = zero16; acc[1] = zero16;

    const int wbase = cq * 256 + h * 64 + kh * 32 + wl;   // write slot (kfl=0); +128 kfl=1
    const int rbase = kh * 512 + h * 64 + wl;             // read base; +kf*128 +nt*32

    // ---- prologue: S(0) -> p[0]; vfA(0); aq(1) ----
    bf16x8 aq = *(const bf16x8*)(qb + (size_t)cq * 512 + qoff);
    uint4 vfA[4], vfB[4];
#pragma unroll
    for (int kf = 0; kf < 4; kf++)
        vfA[kf] = vtb4[(size_t)(kh * 4 + kf) * 256];
    {
        f32x16 s = __builtin_amdgcn_mfma_f32_32x32x16_bf16(aq, bk, zero16, 0, 0, 0);
        aq = *(const bf16x8*)(qb + (size_t)(4 + cq) * 512 + qoff);
        p_lds[0][wbase]       = exp2pkq(s, 0);
        p_lds[0][wbase + 128] = exp2pkq(s, 8);
    }
    __syncthreads();

    // iter it: PV from p[it&1] + vf(it); S(it+1)+exp2 -> p[(it+1)&1]
#define STEP(IT, CUR, VC, VN)                                                        \
    {                                                                                \
        const int it_ = (IT);                                                        \
        int kgb = ((it_ + 1) & 31) * 8 + kh * 4;                                     \
        _Pragma("unroll") for (int kf = 0; kf < 4; kf++)                             \
            VN[kf] = vtb4[(size_t)(kgb + kf) * 256];                                 \
        f32x16 s = __builtin_amdgcn_mfma_f32_32x32x16_bf16(aq, bk, zero16, 0, 0, 0); \
        aq = *(const bf16x8*)(qb + (size_t)(((it_ + 2) & 31) * 4 + cq) * 512 + qoff);\
        __builtin_amdgcn_s_setprio(1);                                               \
        _Pragma("unroll") for (int kf = 0; kf < 4; kf++) {                           \
            bf16x8 af = uint4_as_bf8(VC[kf]);                                        \
            _Pragma("unroll") for (int nt = 0; nt < 2; nt++) {                       \
                bf16x8 bp = uint4_as_bf8(p_lds[CUR][rbase + kf * 128 + nt * 32]);    \
                acc[nt] = __builtin_amdgcn_mfma_f32_32x32x16_bf16(af, bp, acc[nt], 0, 0, 0); \
            }                                                                        \
        }                                                                            \
        __builtin_amdgcn_s_setprio(0);                                               \
        p_lds[(CUR) ^ 1][wbase]       = exp2pkq(s, 0);                               \
        p_lds[(CUR) ^ 1][wbase + 128] = exp2pkq(s, 8);                               \
        __syncthreads();                                                             \
    }

    for (int i2 = 0; i2 < 16; i2++) {
        STEP(2 * i2,     0, vfA, vfB);
        STEP(2 * i2 + 1, 1, vfB, vfA);
    }
#undef STEP

    // ---- epilogue: sum j-half pairs, then coalesced store ----
    // acc C layout: row c = cq*32 + (r&3)+8*(r>>2)+4h, col w = nt*32 + wl
#define CROW(r) (cq * 32 + ((r) & 3) + 8 * ((r) >> 2) + 4 * h)
    if (kh == 1) {
#pragma unroll
        for (int nt = 0; nt < 2; nt++)
#pragma unroll
            for (int r = 0; r < 16; r++)
                red[CROW(r) * 68 + nt * 32 + wl] = acc[nt][r];
    }
    __syncthreads();
    if (kh == 0) {
#pragma unroll
        for (int nt = 0; nt < 2; nt++)
#pragma unroll
            for (int r = 0; r < 16; r++) {
                int o = CROW(r) * 68 + nt * 32 + wl;
                red[o] += acc[nt][r];
            }
    }
#undef CROW
    __syncthreads();

    // coalesced store: out = red + x   (2048 float4 slots / 512 thr)
#pragma unroll
    for (int u = 0; u < 4; u++) {
        int k = tid + 512 * u;
        int c = k >> 4, wseg = (k & 15) * 4;
        size_t gidx = (size_t)(b * C_ + c) * W_ + w0 + wseg;
        float4 xv = *(const float4*)(x + gidx);
        const float* sp = &red[c * 68 + wseg];
        *(float4*)(out + gidx) = make_float4(sp[0] + xv.x, sp[1] + xv.y, sp[2] + xv.z, sp[3] + xv.w);
    }
}

extern "C" void kernel_launch(void* const* d_in, const int* in_sizes, int n_in,
                              void* d_out, int out_size, void* d_ws, size_t ws_size,
                              hipStream_t stream)
{
    const float* x  = (const float*)d_in[0];
    const float* Wq = (const float*)d_in[1];
    const float* bq = (const float*)d_in[2];
    const float* Wk = (const float*)d_in[3];
    const float* bk = (const float*)d_in[4];
    const float* Wv = (const float*)d_in[5];
    const float* bv = (const float*)d_in[6];
    float* out = (float*)d_out;

    unsigned short* qws2 = (unsigned short*)d_ws;        // [B][128][2][32][8] = 1MB
    unsigned short* kws2 = qws2 + (size_t)524288;        // 1MB
    unsigned short* vws2 = kws2 + (size_t)524288;        // [B][128][2][2][128][8] = 8.4MB
    unsigned short* Wvbf = vws2 + (size_t)4194304;       // [128][128]
    unsigned short* Wqkbf = Wvbf + 16384;                // [32][128]

    prep<<<20, 256, 0, stream>>>(Wq, Wk, Wv, Wvbf, Wqkbf);
    proj<<<1024, 256, 0, stream>>>(x, Wvbf, Wqkbf, bq, bk, bv, qws2, kws2, vws2);
    rsv<<<1024, 256, 0, stream>>>(qws2, kws2, vws2);
    attn_out<<<512, 512, 0, stream>>>(x, qws2, kws2, vws2, out);
}